// Round 7
// baseline (160.744 us; speedup 1.0000x reference)
//
#include <hip/hip_runtime.h>
#include <math.h>

#define B   64
#define NV  40000
#define P   100
#define KG  128
#define NJ  24
#define TV  16          // vertices per block/sub-tile
#define NSK 31          // skeleton joints: 1 zero + 23 + 7
#define NSUB (KG / TV)  // 8 sub-tiles per joint

typedef __attribute__((ext_vector_type(8))) short bf16x8;
typedef __attribute__((ext_vector_type(4))) float f32x4;

__device__ __forceinline__ unsigned short rne_bf16(float f) {
  unsigned u = __float_as_uint(f);
  u = (u + 0x7FFFu + ((u >> 16) & 1u)) >> 16;
  return (unsigned short)u;
}

// ---------------------------------------------------------------------------
// Kernel 1: partial joint keypoints, bf16 MFMA. Grid (23, 8).
// A-frags built directly from fp32 beta (L2-hot, predicated k<100) — k_prep
// removed. Block (0,0) additionally writes beta_bf for k_skin (stream order
// guarantees k_skin sees it). sd gather re-tasked: one task per (vertex,k),
// 3 contiguous dword loads -> fewer scattered VMEM instructions.
// ---------------------------------------------------------------------------
__global__ __launch_bounds__(256)
void k_jpart(const float* __restrict__ beta,
             const float* __restrict__ sd,
             const float* __restrict__ vt,
             const int*   __restrict__ joint_idx,
             float*       __restrict__ pmn,
             float*       __restrict__ pmx,
             unsigned short* __restrict__ beta_bf) {
  const int j = blockIdx.x;   // 0..22
  const int s = blockIdx.y;   // 0..7
  const int t = threadIdx.x;  // 0..255
  const int lane = t & 63, wv = t >> 6;
  const int l15 = lane & 15, qd = lane >> 4;

  __shared__ __align__(16) unsigned short sdT_s[48 * 136];  // 13056 B
  __shared__ __align__(16) float pos_s[64 * 68];            // 17408 B
  __shared__ float vt_s[48];
  __shared__ int   idx_s[TV];

  if (t < TV) idx_s[t] = joint_idx[j * KG + s * TV + t];

  // designated block also emits beta_bf[b][136] for k_skin
  if (j == 0 && s == 0) {
    for (int e = t; e < B * 136; e += 256) {
      const int m = e / 136, k = e % 136;
      beta_bf[e] = (k < P) ? rne_bf16(beta[m * P + k]) : (unsigned short)0;
    }
  }
  __syncthreads();

  // zero-fill padding k in [100,128) (28 halfwords x 48 rows)
  for (int e = t; e < 48 * 28; e += 256) {
    const int n = e / 28, k = P + e % 28;
    sdT_s[n * 136 + k] = 0;
  }
  // gather: task (v,k): 3 contiguous dwords at sd[k][idx*3 .. +2]
  for (int task = t; task < TV * P; task += 256) {
    const int v = task / P, k = task % P;
    const float* src = sd + (size_t)k * (3 * NV) + (size_t)idx_s[v] * 3;
    const float f0 = src[0], f1 = src[1], f2 = src[2];
    sdT_s[(v * 3 + 0) * 136 + k] = rne_bf16(f0);
    sdT_s[(v * 3 + 1) * 136 + k] = rne_bf16(f1);
    sdT_s[(v * 3 + 2) * 136 + k] = rne_bf16(f2);
  }
  if (t < 48) vt_s[t] = vt[(size_t)idx_s[t / 3] * 3 + (t % 3)];
  __syncthreads();

  // A-frags direct from fp32 beta (row m = wv*16+l15)
  const int m0 = wv * 16 + l15;
  bf16x8 af[4];
#pragma unroll
  for (int ks = 0; ks < 4; ++ks) {
#pragma unroll
    for (int jj = 0; jj < 8; ++jj) {
      const int k = ks * 32 + qd * 8 + jj;
      af[ks][jj] = (short)((k < P) ? rne_bf16(beta[m0 * P + k]) : (unsigned short)0);
    }
  }

  // D(64x48) = beta(64x128) @ sdT(128x48), wave-per-M-tile
  f32x4 acc[3];
#pragma unroll
  for (int nt = 0; nt < 3; ++nt) acc[nt] = (f32x4){0.f, 0.f, 0.f, 0.f};
#pragma unroll
  for (int ks = 0; ks < 4; ++ks) {
#pragma unroll
    for (int nt = 0; nt < 3; ++nt) {
      const bf16x8 bf = *(const bf16x8*)&sdT_s[(nt * 16 + l15) * 136 + ks * 32 + qd * 8];
      acc[nt] = __builtin_amdgcn_mfma_f32_16x16x32_bf16(af[ks], bf, acc[nt], 0, 0, 0);
    }
  }
  float vtv[3];
#pragma unroll
  for (int nt = 0; nt < 3; ++nt) vtv[nt] = vt_s[nt * 16 + l15];

  // v_posed -> pos_s[b][v*4+c]; C/D layout: col=lane&15, row=quad*4+reg
#pragma unroll
  for (int nt = 0; nt < 3; ++nt) {
    const int n = nt * 16 + l15;
    const int v = n / 3, c = n - 3 * v;
#pragma unroll
    for (int r = 0; r < 4; ++r) {
      const int m = wv * 16 + qd * 4 + r;   // batch
      pos_s[m * 68 + v * 4 + c] = acc[nt][r] + vtv[nt];
    }
  }
  __syncthreads();

  // min/max over the 16 verts: thread t<192 handles (b=t/3, c=t%3)
  if (t < 192) {
    const int b = t / 3, c = t % 3;
    float lo = 1e30f, hi = -1e30f;
#pragma unroll
    for (int v = 0; v < TV; ++v) {
      const float val = pos_s[b * 68 + v * 4 + c];
      lo = fminf(lo, val); hi = fmaxf(hi, val);
    }
    pmn[((j * NSUB + s) * B + b) * 3 + c] = lo;
    pmx[((j * NSUB + s) * B + b) * 3 + c] = hi;
  }
}

// ---------------------------------------------------------------------------
// Kernel 2: J finalize + rodrigues + kinematic chain + translation corr.
// One block per batch, 64 threads. Emits G1A[b][16][32] bf16 (A-operand for
// phase-2 skinning; slot k==24, m%4==3 carries trans).
// ---------------------------------------------------------------------------
__global__ void k_chain(const float* __restrict__ pose,
                        const int*   __restrict__ parent,
                        const float* __restrict__ pmn,
                        const float* __restrict__ pmx,
                        const float* __restrict__ trans,
                        unsigned short* __restrict__ G1A) {
  const int b = blockIdx.x;
  const int t = threadIdx.x;  // 64

  __shared__ float R[NJ][9];
  __shared__ float Jl[NJ][3];
  __shared__ float G[NJ][12];
  __shared__ float G1c[NJ][12];

  if (t < NJ) {
    const float x = pose[b * NJ * 3 + t * 3 + 0];
    const float y = pose[b * NJ * 3 + t * 3 + 1];
    const float z = pose[b * NJ * 3 + t * 3 + 2];
    const float th = fmaxf(sqrtf(x * x + y * y + z * z), 1e-6f);
    const float xh = x / th, yh = y / th, zh = z / th;
    const float c = cosf(th), s = sinf(th), o = 1.0f - c;
    R[t][0] = c + o * xh * xh;      R[t][1] = o * xh * yh - s * zh; R[t][2] = o * xh * zh + s * yh;
    R[t][3] = o * xh * yh + s * zh; R[t][4] = c + o * yh * yh;      R[t][5] = o * yh * zh - s * xh;
    R[t][6] = o * xh * zh - s * yh; R[t][7] = o * yh * zh + s * xh; R[t][8] = c + o * zh * zh;
    if (t == 0) {
      Jl[0][0] = 0.0f; Jl[0][1] = 0.0f; Jl[0][2] = 0.0f;
    } else {
      const int jj = t - 1;
#pragma unroll
      for (int c2 = 0; c2 < 3; ++c2) {
        float lo = 1e30f, hi = -1e30f;
#pragma unroll
        for (int s2 = 0; s2 < NSUB; ++s2) {
          lo = fminf(lo, pmn[((jj * NSUB + s2) * B + b) * 3 + c2]);
          hi = fmaxf(hi, pmx[((jj * NSUB + s2) * B + b) * 3 + c2]);
        }
        Jl[t][c2] = 0.5f * (lo + hi);
      }
    }
  }
  __syncthreads();

  if (t < 12) {
    const int r = t >> 2, c = t & 3;
    G[0][t] = (c < 3) ? R[0][r * 3 + c] : Jl[0][r];
  }
  __syncthreads();

  for (int i = 1; i < NJ; ++i) {
    const int p = parent[i];
    if (t < 12) {
      const int r = t >> 2, c = t & 3;
      const float g0 = G[p][r * 4 + 0];
      const float g1 = G[p][r * 4 + 1];
      const float g2 = G[p][r * 4 + 2];
      float l0, l1, l2, add;
      if (c < 3) {
        l0 = R[i][0 * 3 + c]; l1 = R[i][1 * 3 + c]; l2 = R[i][2 * 3 + c];
        add = 0.0f;
      } else {
        l0 = Jl[i][0] - Jl[p][0]; l1 = Jl[i][1] - Jl[p][1]; l2 = Jl[i][2] - Jl[p][2];
        add = G[p][r * 4 + 3];
      }
      G[i][t] = g0 * l0 + g1 * l1 + g2 * l2 + add;
    }
    __syncthreads();
  }

  for (int e = t; e < NJ * 12; e += 64) {
    const int i = e / 12, rc = e % 12, r = rc >> 2, c = rc & 3;
    float val;
    if (c < 3) {
      val = G[i][rc];
    } else {
      val = G[i][r * 4 + 3] - (G[i][r * 4 + 0] * Jl[i][0] +
                               G[i][r * 4 + 1] * Jl[i][1] +
                               G[i][r * 4 + 2] * Jl[i][2]);
    }
    G1c[i][rc] = val;
  }
  __syncthreads();

  for (int e = t; e < 512; e += 64) {
    const int m = e >> 5, k = e & 31;
    float val = 0.0f;
    if (m < 12) {
      if (k < NJ) val = G1c[k][m];
      else if (k == NJ && (m & 3) == 3) val = trans[b * 3 + (m >> 2)];
    }
    G1A[(size_t)b * 512 + e] = rne_bf16(val);
  }
}

// ---------------------------------------------------------------------------
// Kernel 3: fused shape-blend GEMM + skinning — HYBRID.
// sd is staged through LDS (transpose-at-write, shared by all 4 waves:
// 24 coalesced loads + 3 ds_write_b128 per lane, read back as ds_read_b128);
// everything else (beta_bf A-frags, G1A, w, stores) stays direct-global
// (L2-hot / coalesced), as R6 proved those cheap.
// MFMA layouts (verified): A[m=lane&15][k=quad*8+j],
//   B[k=quad*8+j][n=lane&15], C/D col=lane&15 row=quad*4+reg.
// ---------------------------------------------------------------------------
__global__ __launch_bounds__(256)
void k_skin(const float* __restrict__ sd,
            const float* __restrict__ vt,
            const float* __restrict__ w,
            const unsigned short* __restrict__ beta_bf,
            const unsigned short* __restrict__ G1A,
            float*       __restrict__ out) {
  const int n0v = blockIdx.x * TV;
  const int col0 = n0v * 3;
  const int t  = threadIdx.x;
  const int lane = t & 63, wv = t >> 6;
  const int l15 = lane & 15, q = lane >> 4;

  __shared__ __align__(16) unsigned short sdT_s[48 * 136];  // 13056 B
  __shared__ __align__(16) float vhf[64 * 68];              // 17408 B

  // ---- stage sd tile (transpose+convert), coalesced across n ----
  for (int task = t; task < 768; task += 256) {
    const int n = task % 48, kg = task / 48;
    unsigned pk[4];
#pragma unroll
    for (int h = 0; h < 4; ++h) {
      const int k0 = kg * 8 + 2 * h;
      float f0 = 0.0f, f1 = 0.0f;
      if (k0 < P)     f0 = sd[(size_t)k0 * (3 * NV) + col0 + n];
      if (k0 + 1 < P) f1 = sd[(size_t)(k0 + 1) * (3 * NV) + col0 + n];
      pk[h] = (unsigned)rne_bf16(f0) | ((unsigned)rne_bf16(f1) << 16);
    }
    *(uint4*)&sdT_s[n * 136 + kg * 8] = make_uint4(pk[0], pk[1], pk[2], pk[3]);
  }
  __syncthreads();

  // ---- phase 1: A direct from beta_bf (L2-hot), B from LDS ----
  f32x4 acc[3];
#pragma unroll
  for (int nt = 0; nt < 3; ++nt) acc[nt] = (f32x4){0.f, 0.f, 0.f, 0.f};
#pragma unroll
  for (int ks = 0; ks < 4; ++ks) {
    const bf16x8 af = *(const bf16x8*)&beta_bf[(wv * 16 + l15) * 136 + ks * 32 + q * 8];
#pragma unroll
    for (int nt = 0; nt < 3; ++nt) {
      const bf16x8 bf = *(const bf16x8*)&sdT_s[(nt * 16 + l15) * 136 + ks * 32 + q * 8];
      acc[nt] = __builtin_amdgcn_mfma_f32_16x16x32_bf16(af, bf, acc[nt], 0, 0, 0);
    }
  }
  float vtv[3];
#pragma unroll
  for (int nt = 0; nt < 3; ++nt) vtv[nt] = vt[col0 + nt * 16 + l15];

  // v_posed -> vhf[b][v*4+c] (separate buffer: no extra sync needed)
#pragma unroll
  for (int nt = 0; nt < 3; ++nt) {
    const int n = nt * 16 + l15;
    const int v = n / 3, c = n - 3 * v;
#pragma unroll
    for (int r = 0; r < 4; ++r) {
      const int m = wv * 16 + q * 4 + r;
      vhf[m * 68 + v * 4 + c] = acc[nt][r] + vtv[nt];
    }
  }
  __syncthreads();

  // ---- phase 2 ----
  bf16x8 wf;
  if (q < 3) {
    const float* wrow = &w[(size_t)(n0v + l15) * NJ + q * 8];
    const float4 w0 = *(const float4*)wrow;
    const float4 w1 = *(const float4*)(wrow + 4);
    wf[0] = (short)rne_bf16(w0.x); wf[1] = (short)rne_bf16(w0.y);
    wf[2] = (short)rne_bf16(w0.z); wf[3] = (short)rne_bf16(w0.w);
    wf[4] = (short)rne_bf16(w1.x); wf[5] = (short)rne_bf16(w1.y);
    wf[6] = (short)rne_bf16(w1.z); wf[7] = (short)rne_bf16(w1.w);
  } else {
    wf = (bf16x8){0, 0, 0, 0, 0, 0, 0, 0};
    wf[0] = (short)0x3F80;   // bf16(1.0) at k==24 (trans slot)
  }
  const f32x4 zero = (f32x4){0.f, 0.f, 0.f, 0.f};
#pragma unroll 4
  for (int bi = 0; bi < 16; ++bi) {
    const int b = wv * 16 + bi;
    const bf16x8 gf = *(const bf16x8*)&G1A[(size_t)b * 512 + l15 * 32 + q * 8];
    const f32x4 d = __builtin_amdgcn_mfma_f32_16x16x32_bf16(gf, wf, zero, 0, 0, 0);
    const float4 vh = *(const float4*)&vhf[b * 68 + l15 * 4];
    if (q < 3) {
      out[(size_t)b * (NV * 3) + col0 + l15 * 3 + q] =
          d[0] * vh.x + d[1] * vh.y + d[2] * vh.z + d[3];
    }
  }
}

// ---------------------------------------------------------------------------
// Kernel 4: skeleton keypoints from posed (unchanged).
// ---------------------------------------------------------------------------
__global__ void k_skel(const float* __restrict__ posed,
                       const int*   __restrict__ joint_idx,
                       const int*   __restrict__ add_idx,
                       float*       __restrict__ skel) {
  const int j = blockIdx.x;   // 0..29
  const int b = blockIdx.y;   // 0..63
  const int t = threadIdx.x;  // 0..127
  const int idx = (j < 23) ? joint_idx[j * KG + t] : add_idx[(j - 23) * KG + t];

  const float* p = posed + (size_t)b * NV * 3 + (size_t)idx * 3;
  float mn[3], mx[3];
#pragma unroll
  for (int c = 0; c < 3; ++c) { mn[c] = p[c]; mx[c] = p[c]; }
#pragma unroll
  for (int off = 32; off > 0; off >>= 1) {
#pragma unroll
    for (int c = 0; c < 3; ++c) {
      mn[c] = fminf(mn[c], __shfl_down(mn[c], off));
      mx[c] = fmaxf(mx[c], __shfl_down(mx[c], off));
    }
  }
  __shared__ float s_mn[2][3], s_mx[2][3];
  const int wave = t >> 6, lane = t & 63;
  if (lane == 0) {
#pragma unroll
    for (int c = 0; c < 3; ++c) { s_mn[wave][c] = mn[c]; s_mx[wave][c] = mx[c]; }
  }
  __syncthreads();
  if (t == 0) {
#pragma unroll
    for (int c = 0; c < 3; ++c) {
      float lo = fminf(s_mn[0][c], s_mn[1][c]);
      float hi = fmaxf(s_mx[0][c], s_mx[1][c]);
      skel[(b * NSK + 1 + j) * 3 + c] = 0.5f * (lo + hi);
      if (j == 0) skel[(b * NSK + 0) * 3 + c] = 0.0f;
    }
  }
}

// ---------------------------------------------------------------------------
extern "C" void kernel_launch(void* const* d_in, const int* in_sizes, int n_in,
                              void* d_out, int out_size, void* d_ws, size_t ws_size,
                              hipStream_t stream) {
  const float* beta     = (const float*)d_in[0];
  const float* pose     = (const float*)d_in[1];
  const float* trans    = (const float*)d_in[2];
  const float* sd       = (const float*)d_in[3];
  const float* vt       = (const float*)d_in[4];
  const float* w        = (const float*)d_in[5];
  // d_in[6] = reorder_index (identity arange -> unused)
  const int* parent     = (const int*)d_in[7];
  const int* joint_idx  = (const int*)d_in[8];
  const int* add_idx    = (const int*)d_in[9];

  float* out = (float*)d_out;
  unsigned short* G1A     = (unsigned short*)d_ws;            // 64*512 us
  unsigned short* beta_bf = G1A + B * 512;                    // 64*136 us
  float* pmn = (float*)(beta_bf + B * 136);                   // 23*8*64*3 f
  float* pmx = pmn + 23 * NSUB * B * 3;

  k_jpart<<<dim3(23, NSUB), 256, 0, stream>>>(beta, sd, vt, joint_idx,
                                              pmn, pmx, beta_bf);
  k_chain<<<B, 64, 0, stream>>>(pose, parent, pmn, pmx, trans, G1A);
  k_skin <<<NV / TV, 256, 0, stream>>>(sd, vt, w, beta_bf, G1A, out);
  k_skel <<<dim3(30, B), 128, 0, stream>>>(out, joint_idx, add_idx,
                                           out + (size_t)B * NV * 3);
}

// Round 8
// 158.242 us; speedup vs baseline: 1.0158x; 1.0158x over previous
//
#include <hip/hip_runtime.h>
#include <math.h>

#define B   64
#define NV  40000
#define P   100
#define KG  128
#define NJ  24
#define TV  16          // vertices per block/sub-tile
#define NSK 31          // skeleton joints: 1 zero + 23 + 7
#define NSUB (KG / TV)  // 8 sub-tiles per row
#define NROW 30         // 23 joint rows + 7 add rows
#define VPT  (64 * 68)  // vposed tile floats per (row,sub)

typedef __attribute__((ext_vector_type(8))) short bf16x8;
typedef __attribute__((ext_vector_type(4))) float f32x4;

__device__ __forceinline__ unsigned short rne_bf16(float f) {
  unsigned u = __float_as_uint(f);
  u = (u + 0x7FFFu + ((u >> 16) & 1u)) >> 16;
  return (unsigned short)u;
}

// ---------------------------------------------------------------------------
// Kernel 0: beta -> bf16 padded A-rows [b][136] (k<100 real, rest 0).
// Consumed as direct global A-fragments by k_jpart and k_skin (L2-hot).
// ---------------------------------------------------------------------------
__global__ void k_prep(const float* __restrict__ beta,
                       unsigned short* __restrict__ beta_bf) {
  const int t = blockIdx.x * 256 + threadIdx.x;
  if (t < B * 136) {
    const int m = t / 136, k = t % 136;
    beta_bf[t] = (k < P) ? rne_bf16(beta[m * P + k]) : (unsigned short)0;
  }
}

// ---------------------------------------------------------------------------
// Kernel 1: gathered v_posed tiles + partial joint keypoints. Grid (30, 8).
// Rows 0..22 = joint_idx (also emit pmn/pmx partials for J); rows 23..29 =
// add_idx (skeleton only). Every block writes its 64x68 v_posed tile to ws
// for k_skel2. A-frags direct from beta_bf (4 vector loads, fixes R7's
// 32-scalar-load regression). sd gather: one task per (vertex,k), 3
// contiguous dwords.
// ---------------------------------------------------------------------------
__global__ __launch_bounds__(256)
void k_jpart(const unsigned short* __restrict__ beta_bf,
             const float* __restrict__ sd,
             const float* __restrict__ vt,
             const int*   __restrict__ joint_idx,
             const int*   __restrict__ add_idx,
             float*       __restrict__ pmn,
             float*       __restrict__ pmx,
             float*       __restrict__ vposed) {
  const int j = blockIdx.x;   // 0..29
  const int s = blockIdx.y;   // 0..7
  const int t = threadIdx.x;  // 0..255
  const int lane = t & 63, wv = t >> 6;
  const int l15 = lane & 15, qd = lane >> 4;

  __shared__ __align__(16) unsigned short sdT_s[48 * 136];  // 13056 B
  __shared__ __align__(16) float pos_s[64 * 68];            // 17408 B
  __shared__ float vt_s[48];
  __shared__ int   idx_s[TV];

  if (t < TV)
    idx_s[t] = (j < 23) ? joint_idx[j * KG + s * TV + t]
                        : add_idx[(j - 23) * KG + s * TV + t];
  __syncthreads();

  // zero-fill padding k in [100,128)
  for (int e = t; e < 48 * 28; e += 256) {
    const int n = e / 28, k = P + e % 28;
    sdT_s[n * 136 + k] = 0;
  }
  // gather: task (v,k): 3 contiguous dwords at sd[k][idx*3 .. +2]
  for (int task = t; task < TV * P; task += 256) {
    const int v = task / P, k = task % P;
    const float* src = sd + (size_t)k * (3 * NV) + (size_t)idx_s[v] * 3;
    const float f0 = src[0], f1 = src[1], f2 = src[2];
    sdT_s[(v * 3 + 0) * 136 + k] = rne_bf16(f0);
    sdT_s[(v * 3 + 1) * 136 + k] = rne_bf16(f1);
    sdT_s[(v * 3 + 2) * 136 + k] = rne_bf16(f2);
  }
  if (t < 48) vt_s[t] = vt[(size_t)idx_s[t / 3] * 3 + (t % 3)];
  __syncthreads();

  // D(64x48) = beta(64x128) @ sdT(128x48), wave-per-M-tile
  f32x4 acc[3];
#pragma unroll
  for (int nt = 0; nt < 3; ++nt) acc[nt] = (f32x4){0.f, 0.f, 0.f, 0.f};
#pragma unroll
  for (int ks = 0; ks < 4; ++ks) {
    const bf16x8 af = *(const bf16x8*)&beta_bf[(wv * 16 + l15) * 136 + ks * 32 + qd * 8];
#pragma unroll
    for (int nt = 0; nt < 3; ++nt) {
      const bf16x8 bf = *(const bf16x8*)&sdT_s[(nt * 16 + l15) * 136 + ks * 32 + qd * 8];
      acc[nt] = __builtin_amdgcn_mfma_f32_16x16x32_bf16(af, bf, acc[nt], 0, 0, 0);
    }
  }
  float vtv[3];
#pragma unroll
  for (int nt = 0; nt < 3; ++nt) vtv[nt] = vt_s[nt * 16 + l15];

  // v_posed -> pos_s[b][v*4+c]; C/D layout: col=lane&15, row=quad*4+reg
#pragma unroll
  for (int nt = 0; nt < 3; ++nt) {
    const int n = nt * 16 + l15;
    const int v = n / 3, c = n - 3 * v;
#pragma unroll
    for (int r = 0; r < 4; ++r) {
      const int m = wv * 16 + qd * 4 + r;   // batch
      pos_s[m * 68 + v * 4 + c] = acc[nt][r] + vtv[nt];
    }
  }
  __syncthreads();

  // dump tile for k_skel2 (coalesced float4)
  {
    float4* dst = (float4*)(vposed + (size_t)(j * NSUB + s) * VPT);
    const float4* srcp = (const float4*)pos_s;
    for (int e = t; e < VPT / 4; e += 256) dst[e] = srcp[e];
  }

  // min/max over the 16 verts for J (joint rows only)
  if (j < 23 && t < 192) {
    const int b = t / 3, c = t % 3;
    float lo = 1e30f, hi = -1e30f;
#pragma unroll
    for (int v = 0; v < TV; ++v) {
      const float val = pos_s[b * 68 + v * 4 + c];
      lo = fminf(lo, val); hi = fmaxf(hi, val);
    }
    pmn[((j * NSUB + s) * B + b) * 3 + c] = lo;
    pmx[((j * NSUB + s) * B + b) * 3 + c] = hi;
  }
}

// ---------------------------------------------------------------------------
// Kernel 2: J finalize + rodrigues + kinematic chain + translation corr.
// One block per batch, 64 threads. Emits G1A[b][16][32] bf16 (A-operand for
// phase-2 skinning; slot k==24, m%4==3 carries trans).
// ---------------------------------------------------------------------------
__global__ void k_chain(const float* __restrict__ pose,
                        const int*   __restrict__ parent,
                        const float* __restrict__ pmn,
                        const float* __restrict__ pmx,
                        const float* __restrict__ trans,
                        unsigned short* __restrict__ G1A) {
  const int b = blockIdx.x;
  const int t = threadIdx.x;  // 64

  __shared__ float R[NJ][9];
  __shared__ float Jl[NJ][3];
  __shared__ float G[NJ][12];
  __shared__ float G1c[NJ][12];

  if (t < NJ) {
    const float x = pose[b * NJ * 3 + t * 3 + 0];
    const float y = pose[b * NJ * 3 + t * 3 + 1];
    const float z = pose[b * NJ * 3 + t * 3 + 2];
    const float th = fmaxf(sqrtf(x * x + y * y + z * z), 1e-6f);
    const float xh = x / th, yh = y / th, zh = z / th;
    const float c = cosf(th), s = sinf(th), o = 1.0f - c;
    R[t][0] = c + o * xh * xh;      R[t][1] = o * xh * yh - s * zh; R[t][2] = o * xh * zh + s * yh;
    R[t][3] = o * xh * yh + s * zh; R[t][4] = c + o * yh * yh;      R[t][5] = o * yh * zh - s * xh;
    R[t][6] = o * xh * zh - s * yh; R[t][7] = o * yh * zh + s * xh; R[t][8] = c + o * zh * zh;
    if (t == 0) {
      Jl[0][0] = 0.0f; Jl[0][1] = 0.0f; Jl[0][2] = 0.0f;
    } else {
      const int jj = t - 1;
#pragma unroll
      for (int c2 = 0; c2 < 3; ++c2) {
        float lo = 1e30f, hi = -1e30f;
#pragma unroll
        for (int s2 = 0; s2 < NSUB; ++s2) {
          lo = fminf(lo, pmn[((jj * NSUB + s2) * B + b) * 3 + c2]);
          hi = fmaxf(hi, pmx[((jj * NSUB + s2) * B + b) * 3 + c2]);
        }
        Jl[t][c2] = 0.5f * (lo + hi);
      }
    }
  }
  __syncthreads();

  if (t < 12) {
    const int r = t >> 2, c = t & 3;
    G[0][t] = (c < 3) ? R[0][r * 3 + c] : Jl[0][r];
  }
  __syncthreads();

  for (int i = 1; i < NJ; ++i) {
    const int p = parent[i];
    if (t < 12) {
      const int r = t >> 2, c = t & 3;
      const float g0 = G[p][r * 4 + 0];
      const float g1 = G[p][r * 4 + 1];
      const float g2 = G[p][r * 4 + 2];
      float l0, l1, l2, add;
      if (c < 3) {
        l0 = R[i][0 * 3 + c]; l1 = R[i][1 * 3 + c]; l2 = R[i][2 * 3 + c];
        add = 0.0f;
      } else {
        l0 = Jl[i][0] - Jl[p][0]; l1 = Jl[i][1] - Jl[p][1]; l2 = Jl[i][2] - Jl[p][2];
        add = G[p][r * 4 + 3];
      }
      G[i][t] = g0 * l0 + g1 * l1 + g2 * l2 + add;
    }
    __syncthreads();
  }

  for (int e = t; e < NJ * 12; e += 64) {
    const int i = e / 12, rc = e % 12, r = rc >> 2, c = rc & 3;
    float val;
    if (c < 3) {
      val = G[i][rc];
    } else {
      val = G[i][r * 4 + 3] - (G[i][r * 4 + 0] * Jl[i][0] +
                               G[i][r * 4 + 1] * Jl[i][1] +
                               G[i][r * 4 + 2] * Jl[i][2]);
    }
    G1c[i][rc] = val;
  }
  __syncthreads();

  for (int e = t; e < 512; e += 64) {
    const int m = e >> 5, k = e & 31;
    float val = 0.0f;
    if (m < 12) {
      if (k < NJ) val = G1c[k][m];
      else if (k == NJ && (m & 3) == 3) val = trans[b * 3 + (m >> 2)];
    }
    G1A[(size_t)b * 512 + e] = rne_bf16(val);
  }
}

// ---------------------------------------------------------------------------
// Kernel 3: skeleton partials from saved v_posed tiles. Grid (30, 8).
// Replays k_skin's phase 2 (same G1A MFMA + trans slot, identical
// arithmetic) on the coalesced vposed tiles — no scattered reads of `out`,
// no dependency on k_skin.
// ---------------------------------------------------------------------------
__global__ __launch_bounds__(256)
void k_skel2(const float* __restrict__ vposed,
             const float* __restrict__ w,
             const int*   __restrict__ joint_idx,
             const int*   __restrict__ add_idx,
             const unsigned short* __restrict__ G1A,
             float*       __restrict__ pmn2,
             float*       __restrict__ pmx2) {
  const int j = blockIdx.x;   // 0..29
  const int s = blockIdx.y;   // 0..7
  const int t = threadIdx.x;
  const int lane = t & 63, wv = t >> 6;
  const int l15 = lane & 15, q = lane >> 4;

  __shared__ __align__(16) float vhf[64 * 68];    // 17408 B
  __shared__ __align__(16) float pos_s[64 * 68];  // 17408 B
  __shared__ int idx_s[TV];

  if (t < TV)
    idx_s[t] = (j < 23) ? joint_idx[j * KG + s * TV + t]
                        : add_idx[(j - 23) * KG + s * TV + t];
  {
    const float4* srcp = (const float4*)(vposed + (size_t)(j * NSUB + s) * VPT);
    float4* dst = (float4*)vhf;
    for (int e = t; e < VPT / 4; e += 256) dst[e] = srcp[e];
  }
  __syncthreads();

  // w-frag: lane (vert=l15, q): k=q*8+jj; q==3 holds {1,0,...} (trans slot)
  bf16x8 wf;
  if (q < 3) {
    const float* wrow = &w[(size_t)idx_s[l15] * NJ + q * 8];
    const float4 w0 = *(const float4*)wrow;
    const float4 w1 = *(const float4*)(wrow + 4);
    wf[0] = (short)rne_bf16(w0.x); wf[1] = (short)rne_bf16(w0.y);
    wf[2] = (short)rne_bf16(w0.z); wf[3] = (short)rne_bf16(w0.w);
    wf[4] = (short)rne_bf16(w1.x); wf[5] = (short)rne_bf16(w1.y);
    wf[6] = (short)rne_bf16(w1.z); wf[7] = (short)rne_bf16(w1.w);
  } else {
    wf = (bf16x8){0, 0, 0, 0, 0, 0, 0, 0};
    wf[0] = (short)0x3F80;   // bf16(1.0) at k==24
  }
  const f32x4 zero = (f32x4){0.f, 0.f, 0.f, 0.f};
#pragma unroll 4
  for (int bi = 0; bi < 16; ++bi) {
    const int b = wv * 16 + bi;
    const bf16x8 gf = *(const bf16x8*)&G1A[(size_t)b * 512 + l15 * 32 + q * 8];
    const f32x4 d = __builtin_amdgcn_mfma_f32_16x16x32_bf16(gf, wf, zero, 0, 0, 0);
    const float4 vh = *(const float4*)&vhf[b * 68 + l15 * 4];
    if (q < 3) {
      pos_s[b * 68 + l15 * 4 + q] =
          d[0] * vh.x + d[1] * vh.y + d[2] * vh.z + d[3];
    }
  }
  __syncthreads();

  if (t < 192) {
    const int b = t / 3, c = t % 3;
    float lo = 1e30f, hi = -1e30f;
#pragma unroll
    for (int v = 0; v < TV; ++v) {
      const float val = pos_s[b * 68 + v * 4 + c];
      lo = fminf(lo, val); hi = fmaxf(hi, val);
    }
    pmn2[((j * NSUB + s) * B + b) * 3 + c] = lo;
    pmx2[((j * NSUB + s) * B + b) * 3 + c] = hi;
  }
}

// ---------------------------------------------------------------------------
// Kernel 3b: skeleton finalize — 8-way reduce + zero row. Grid 30 x 192.
// ---------------------------------------------------------------------------
__global__ void k_skelfin(const float* __restrict__ pmn2,
                          const float* __restrict__ pmx2,
                          float*       __restrict__ skel) {
  const int tg = blockIdx.x * 192 + threadIdx.x;  // 0..5759
  const int j = tg / (B * 3);
  const int rem = tg % (B * 3);
  const int b = rem / 3, c = rem % 3;
  float lo = 1e30f, hi = -1e30f;
#pragma unroll
  for (int s = 0; s < NSUB; ++s) {
    lo = fminf(lo, pmn2[((j * NSUB + s) * B + b) * 3 + c]);
    hi = fmaxf(hi, pmx2[((j * NSUB + s) * B + b) * 3 + c]);
  }
  skel[(b * NSK + 1 + j) * 3 + c] = 0.5f * (lo + hi);
  if (j == 0) skel[(b * NSK + 0) * 3 + c] = 0.0f;
}

// ---------------------------------------------------------------------------
// Kernel 4: fused shape-blend GEMM + skinning — HYBRID (unchanged from R7).
// sd staged through LDS (shared by 4 waves); beta_bf/G1A/w direct global
// (L2-hot); direct coalesced stores.
// ---------------------------------------------------------------------------
__global__ __launch_bounds__(256)
void k_skin(const float* __restrict__ sd,
            const float* __restrict__ vt,
            const float* __restrict__ w,
            const unsigned short* __restrict__ beta_bf,
            const unsigned short* __restrict__ G1A,
            float*       __restrict__ out) {
  const int n0v = blockIdx.x * TV;
  const int col0 = n0v * 3;
  const int t  = threadIdx.x;
  const int lane = t & 63, wv = t >> 6;
  const int l15 = lane & 15, q = lane >> 4;

  __shared__ __align__(16) unsigned short sdT_s[48 * 136];  // 13056 B
  __shared__ __align__(16) float vhf[64 * 68];              // 17408 B

  for (int task = t; task < 768; task += 256) {
    const int n = task % 48, kg = task / 48;
    unsigned pk[4];
#pragma unroll
    for (int h = 0; h < 4; ++h) {
      const int k0 = kg * 8 + 2 * h;
      float f0 = 0.0f, f1 = 0.0f;
      if (k0 < P)     f0 = sd[(size_t)k0 * (3 * NV) + col0 + n];
      if (k0 + 1 < P) f1 = sd[(size_t)(k0 + 1) * (3 * NV) + col0 + n];
      pk[h] = (unsigned)rne_bf16(f0) | ((unsigned)rne_bf16(f1) << 16);
    }
    *(uint4*)&sdT_s[n * 136 + kg * 8] = make_uint4(pk[0], pk[1], pk[2], pk[3]);
  }
  __syncthreads();

  f32x4 acc[3];
#pragma unroll
  for (int nt = 0; nt < 3; ++nt) acc[nt] = (f32x4){0.f, 0.f, 0.f, 0.f};
#pragma unroll
  for (int ks = 0; ks < 4; ++ks) {
    const bf16x8 af = *(const bf16x8*)&beta_bf[(wv * 16 + l15) * 136 + ks * 32 + q * 8];
#pragma unroll
    for (int nt = 0; nt < 3; ++nt) {
      const bf16x8 bf = *(const bf16x8*)&sdT_s[(nt * 16 + l15) * 136 + ks * 32 + q * 8];
      acc[nt] = __builtin_amdgcn_mfma_f32_16x16x32_bf16(af, bf, acc[nt], 0, 0, 0);
    }
  }
  float vtv[3];
#pragma unroll
  for (int nt = 0; nt < 3; ++nt) vtv[nt] = vt[col0 + nt * 16 + l15];

#pragma unroll
  for (int nt = 0; nt < 3; ++nt) {
    const int n = nt * 16 + l15;
    const int v = n / 3, c = n - 3 * v;
#pragma unroll
    for (int r = 0; r < 4; ++r) {
      const int m = wv * 16 + q * 4 + r;
      vhf[m * 68 + v * 4 + c] = acc[nt][r] + vtv[nt];
    }
  }
  __syncthreads();

  bf16x8 wf;
  if (q < 3) {
    const float* wrow = &w[(size_t)(n0v + l15) * NJ + q * 8];
    const float4 w0 = *(const float4*)wrow;
    const float4 w1 = *(const float4*)(wrow + 4);
    wf[0] = (short)rne_bf16(w0.x); wf[1] = (short)rne_bf16(w0.y);
    wf[2] = (short)rne_bf16(w0.z); wf[3] = (short)rne_bf16(w0.w);
    wf[4] = (short)rne_bf16(w1.x); wf[5] = (short)rne_bf16(w1.y);
    wf[6] = (short)rne_bf16(w1.z); wf[7] = (short)rne_bf16(w1.w);
  } else {
    wf = (bf16x8){0, 0, 0, 0, 0, 0, 0, 0};
    wf[0] = (short)0x3F80;   // bf16(1.0) at k==24 (trans slot)
  }
  const f32x4 zero = (f32x4){0.f, 0.f, 0.f, 0.f};
#pragma unroll 4
  for (int bi = 0; bi < 16; ++bi) {
    const int b = wv * 16 + bi;
    const bf16x8 gf = *(const bf16x8*)&G1A[(size_t)b * 512 + l15 * 32 + q * 8];
    const f32x4 d = __builtin_amdgcn_mfma_f32_16x16x32_bf16(gf, wf, zero, 0, 0, 0);
    const float4 vh = *(const float4*)&vhf[b * 68 + l15 * 4];
    if (q < 3) {
      out[(size_t)b * (NV * 3) + col0 + l15 * 3 + q] =
          d[0] * vh.x + d[1] * vh.y + d[2] * vh.z + d[3];
    }
  }
}

// ---------------------------------------------------------------------------
extern "C" void kernel_launch(void* const* d_in, const int* in_sizes, int n_in,
                              void* d_out, int out_size, void* d_ws, size_t ws_size,
                              hipStream_t stream) {
  const float* beta     = (const float*)d_in[0];
  const float* pose     = (const float*)d_in[1];
  const float* trans    = (const float*)d_in[2];
  const float* sd       = (const float*)d_in[3];
  const float* vt       = (const float*)d_in[4];
  const float* w        = (const float*)d_in[5];
  // d_in[6] = reorder_index (identity arange -> unused)
  const int* parent     = (const int*)d_in[7];
  const int* joint_idx  = (const int*)d_in[8];
  const int* add_idx    = (const int*)d_in[9];

  float* out = (float*)d_out;
  unsigned short* G1A     = (unsigned short*)d_ws;            // 32768 us
  unsigned short* beta_bf = G1A + B * 512;                    //  8704 us
  float* pmn    = (float*)(beta_bf + B * 136);                // 23*8*64*3
  float* pmx    = pmn + 23 * NSUB * B * 3;
  float* pmn2   = pmx + 23 * NSUB * B * 3;                    // 30*8*64*3
  float* pmx2   = pmn2 + NROW * NSUB * B * 3;
  float* vposed = pmx2 + NROW * NSUB * B * 3;                 // 30*8*4352

  k_prep  <<<(B * 136 + 255) / 256, 256, 0, stream>>>(beta, beta_bf);
  k_jpart <<<dim3(NROW, NSUB), 256, 0, stream>>>(beta_bf, sd, vt, joint_idx,
                                                 add_idx, pmn, pmx, vposed);
  k_chain <<<B, 64, 0, stream>>>(pose, parent, pmn, pmx, trans, G1A);
  k_skel2 <<<dim3(NROW, NSUB), 256, 0, stream>>>(vposed, w, joint_idx, add_idx,
                                                 G1A, pmn2, pmx2);
  k_skelfin<<<NROW, 192, 0, stream>>>(pmn2, pmx2, out + (size_t)B * NV * 3);
  k_skin  <<<NV / TV, 256, 0, stream>>>(sd, vt, w, beta_bf, G1A, out);
}